// Round 14
// baseline (309.293 us; speedup 1.0000x reference)
//
#include <hip/hip_runtime.h>
#include <math.h>

#define NN 50000
#define NE 800000
#define TM 16
#define NPAN 4
#define PSZ 12500   // nodes per src panel (3.2 MB of f16 rows, fits 4MB L2)
#define NT (NN * NPAN)
#define SCH 1024
#define NSB ((NT + SCH - 1) / SCH)   // 196 scan blocks

typedef _Float16 half4v __attribute__((ext_vector_type(4)));
typedef _Float16 half8v __attribute__((ext_vector_type(8)));
typedef float f32x4 __attribute__((ext_vector_type(4)));

__device__ __forceinline__ float relu(float v) { return fmaxf(v, 0.0f); }

// ---- degree count per (dst, src-panel) ----
__global__ __launch_bounds__(256) void k_deg2(const int* __restrict__ ei,
                                              int* __restrict__ deg2) {
  int e = blockIdx.x * 256 + threadIdx.x;
  if (e < NE) {
    int s = ei[e];
    int d = ei[NE + e];
    atomicAdd(&deg2[d * NPAN + s / PSZ], 1);
  }
}

// ---- d^-1/2 from panel-bucket degrees ----
__global__ __launch_bounds__(256) void k_dinv(const int* __restrict__ deg2,
                                              float* __restrict__ dinv) {
  int i = blockIdx.x * 256 + threadIdx.x;
  if (i < NN) {
    int d = deg2[i * NPAN] + deg2[i * NPAN + 1] + deg2[i * NPAN + 2] +
            deg2[i * NPAN + 3];
    dinv[i] = d > 0 ? 1.0f / sqrtf((float)d) : 0.0f;
  }
}

// ---- hierarchical scan, phase A: per-block chunk sums ----
__global__ __launch_bounds__(256) void k_scanA(const int* __restrict__ deg2,
                                               int* __restrict__ bsum) {
  const int tid = threadIdx.x;
  const int lane = tid & 63;
  const int wid = tid >> 6;
  int base = blockIdx.x * SCH + tid * 4;
  int s = 0;
  if (base + 3 < NT) {
    int4 v = *(const int4*)&deg2[base];
    s = v.x + v.y + v.z + v.w;
  } else {
#pragma unroll
    for (int j = 0; j < 4; ++j)
      if (base + j < NT) s += deg2[base + j];
  }
#pragma unroll
  for (int off = 1; off < 64; off <<= 1) s += __shfl_xor(s, off);
  __shared__ int ws[4];
  if (lane == 0) ws[wid] = s;
  __syncthreads();
  if (tid == 0) bsum[blockIdx.x] = ws[0] + ws[1] + ws[2] + ws[3];
}

// ---- phase B: single block exclusive-scans the NSB block sums ----
__global__ __launch_bounds__(256) void k_scanB(const int* __restrict__ bsum,
                                               int* __restrict__ boff,
                                               int* __restrict__ rowptr2) {
  const int tid = threadIdx.x;
  const int lane = tid & 63;
  const int wid = tid >> 6;
  int v = (tid < NSB) ? bsum[tid] : 0;
  int sum = v;
#pragma unroll
  for (int off = 1; off < 64; off <<= 1) {
    int t = __shfl_up(sum, off);
    if (lane >= off) sum += t;
  }
  __shared__ int ws[4];
  if (lane == 63) ws[wid] = sum;
  __syncthreads();
  int wbase = 0;
  for (int w = 0; w < wid; ++w) wbase += ws[w];
  int ex = wbase + sum - v;
  if (tid < NSB) boff[tid] = ex;
  if (tid == NSB - 1) rowptr2[NT] = ex + v;
}

// ---- phase C: per-block local exclusive scan + block offset ----
__global__ __launch_bounds__(256) void k_scanC(const int* __restrict__ deg2,
                                               const int* __restrict__ boff,
                                               int* __restrict__ rowptr2) {
  const int tid = threadIdx.x;
  const int lane = tid & 63;
  const int wid = tid >> 6;
  int base = blockIdx.x * SCH + tid * 4;
  int v0 = 0, v1 = 0, v2 = 0, v3 = 0;
  if (base + 3 < NT) {
    int4 v = *(const int4*)&deg2[base];
    v0 = v.x; v1 = v.y; v2 = v.z; v3 = v.w;
  } else {
    if (base + 0 < NT) v0 = deg2[base + 0];
    if (base + 1 < NT) v1 = deg2[base + 1];
    if (base + 2 < NT) v2 = deg2[base + 2];
    if (base + 3 < NT) v3 = deg2[base + 3];
  }
  int tsum = v0 + v1 + v2 + v3;
  int sum = tsum;
#pragma unroll
  for (int off = 1; off < 64; off <<= 1) {
    int t = __shfl_up(sum, off);
    if (lane >= off) sum += t;
  }
  __shared__ int ws[4];
  if (lane == 63) ws[wid] = sum;
  __syncthreads();
  int wbase = 0;
  for (int w = 0; w < wid; ++w) wbase += ws[w];
  int ex = boff[blockIdx.x] + wbase + sum - tsum;
  if (base + 0 < NT) rowptr2[base + 0] = ex;
  if (base + 1 < NT) rowptr2[base + 1] = ex + v0;
  if (base + 2 < NT) rowptr2[base + 2] = ex + v0 + v1;
  if (base + 3 < NT) rowptr2[base + 3] = ex + v0 + v1 + v2;
}

// ---- CSR fill into (dst, panel) buckets + edge weights ----
__global__ __launch_bounds__(256) void k_fill(const int* __restrict__ ei,
                                              const float* __restrict__ dinv,
                                              const int* __restrict__ rowptr2,
                                              int* __restrict__ fill2,
                                              int* __restrict__ col,
                                              float* __restrict__ wgt) {
  int e = blockIdx.x * 256 + threadIdx.x;
  if (e < NE) {
    int s = ei[e];
    int d = ei[NE + e];
    float w = dinv[s] * dinv[d] * 0.5f;
    int b = d * NPAN + s / PSZ;
    int pos = rowptr2[b] + atomicAdd(&fill2[b], 1);
    col[pos] = s;
    wgt[pos] = w;
  }
}

// ---- x (f32) -> xh (f16 [N][128]) ----
__global__ __launch_bounds__(256) void k_x2h(const float* __restrict__ x,
                                             _Float16* __restrict__ xh) {
  int i = blockIdx.x * 256 + threadIdx.x;
  if (i < NN * 32) {
    float4 v = ((const float4*)x)[i];
    half4v h;
    h[0] = (_Float16)v.x; h[1] = (_Float16)v.y;
    h[2] = (_Float16)v.z; h[3] = (_Float16)v.w;
    ((half4v*)xh)[i] = h;
  }
}

// ---- one hop: 16 lanes/node; 8 gathers in flight; shfl-broadcast edges ----
__global__ __launch_bounds__(256) void k_hop16(const _Float16* __restrict__ in,
                                               _Float16* __restrict__ out,
                                               const int* __restrict__ rowptr2,
                                               const int* __restrict__ col,
                                               const float* __restrict__ wgt) {
  int g = (blockIdx.x * 256 + threadIdx.x) >> 4;  // node, 16 threads/node
  int lane = threadIdx.x & 15;
  if (g >= NN) return;
  const half8v* in8 = (const half8v*)in;  // 16B per lane, 256B per row
  half8v a = in8[(size_t)g * 16 + lane];
  float acc[8];
#pragma unroll
  for (int j = 0; j < 8; ++j) acc[j] = 0.5f * (float)a[j];
  int e0 = rowptr2[g * NPAN];
  int e1 = rowptr2[g * NPAN + NPAN];
  for (int base = e0; base < e1; base += 16) {
    int idx = base + lane;
    int idxc = idx < e1 ? idx : e1 - 1;   // clamp (value unused when masked)
    int cv = col[idxc];
    float wv = wgt[idxc];
    int cnt = e1 - base;
    if (cnt > 16) cnt = 16;
    int j = 0;
    for (; j + 8 <= cnt; j += 8) {
      int cc[8];
      float ww[8];
#pragma unroll
      for (int q = 0; q < 8; ++q) {
        cc[q] = __shfl(cv, j + q, 16);
        ww[q] = __shfl(wv, j + q, 16);
      }
      half8v vv[8];
#pragma unroll
      for (int q = 0; q < 8; ++q) vv[q] = in8[(size_t)cc[q] * 16 + lane];
#pragma unroll
      for (int q = 0; q < 8; ++q)
#pragma unroll
        for (int k = 0; k < 8; ++k) acc[k] += ww[q] * (float)vv[q][k];
    }
    for (; j + 4 <= cnt; j += 4) {
      int c0 = __shfl(cv, j, 16), c1 = __shfl(cv, j + 1, 16);
      int c2 = __shfl(cv, j + 2, 16), c3 = __shfl(cv, j + 3, 16);
      float w0 = __shfl(wv, j, 16), w1 = __shfl(wv, j + 1, 16);
      float w2 = __shfl(wv, j + 2, 16), w3 = __shfl(wv, j + 3, 16);
      half8v v0 = in8[(size_t)c0 * 16 + lane];
      half8v v1 = in8[(size_t)c1 * 16 + lane];
      half8v v2 = in8[(size_t)c2 * 16 + lane];
      half8v v3 = in8[(size_t)c3 * 16 + lane];
#pragma unroll
      for (int k = 0; k < 8; ++k)
        acc[k] += w0 * (float)v0[k] + w1 * (float)v1[k] +
                  w2 * (float)v2[k] + w3 * (float)v3[k];
    }
    for (; j < cnt; ++j) {
      int c = __shfl(cv, j, 16);
      float w = __shfl(wv, j, 16);
      half8v v = in8[(size_t)c * 16 + lane];
#pragma unroll
      for (int k = 0; k < 8; ++k) acc[k] += w * (float)v[k];
    }
  }
  half8v r;
#pragma unroll
  for (int j = 0; j < 8; ++j) r[j] = (_Float16)acc[j];
  ((half8v*)out)[(size_t)g * 16 + lane] = r;
}

// ---- prep: weights -> f16 fragment-order [m][ct(8)][ks(4)][lane(64)][8] ----
__global__ __launch_bounds__(256) void k_prep(const float* __restrict__ W_low,
                                              const float* __restrict__ W_band,
                                              const float* __restrict__ W_mlp,
                                              _Float16* __restrict__ WTs) {
  int m = blockIdx.x;  // 0..6 channels, 7..8 mlp chunks
  const float* src;
  if (m < 4)      src = W_low + m * 16384;
  else if (m < 7) src = W_band + (m - 4) * 16384;
  else            src = W_mlp + (m - 7) * 16384;
  _Float16* dst = WTs + (size_t)m * 16384;
  for (int s = threadIdx.x; s < 2048; s += 256) {
    int ct = s >> 8;          // col tile 0..7
    int ks = (s >> 6) & 3;    // k step 0..3
    int lane = s & 63;
    int mcol = lane & 15, kg = lane >> 4;
    int colc = ct * 16 + mcol;
    int k0 = ks * 32 + 4 * kg;
    _Float16* d = dst + (size_t)s * 8;
#pragma unroll
    for (int j = 0; j < 4; ++j) d[j] = (_Float16)src[(k0 + j) * 128 + colc];
#pragma unroll
    for (int j = 0; j < 4; ++j) d[4 + j] = (_Float16)src[(k0 + 16 + j) * 128 + colc];
  }
}

// ---- fused MFMA: 7-ch GEMM + single-pass register attention + MLP ----
__global__ __launch_bounds__(256, 3) void k_fused(
    const _Float16* __restrict__ xh, const _Float16* __restrict__ a1,
    const _Float16* __restrict__ a2, const _Float16* __restrict__ a4,
    const _Float16* __restrict__ WTs,
    const float* __restrict__ b_low, const float* __restrict__ b_band,
    const float* __restrict__ apre_l, const float* __restrict__ ach_l,
    const float* __restrict__ apre_b, const float* __restrict__ ach_b,
    const float* __restrict__ b_mlp, float* __restrict__ out) {
  __shared__ _Float16 sH[7][TM][136]; // channel outputs  30464 B
  __shared__ _Float16 sV[TM][264];    // MLP input         8448 B

  const int tid = threadIdx.x;
  const int wid = tid >> 6;
  const int lane = tid & 63;
  const int mrow = lane & 15;   // node row in tile / out col in 16-tile
  const int kg = lane >> 4;     // k-group 0..3
  const int node0 = blockIdx.x * TM;
  const int colw = wid * 32;    // wave's 32-col slice (coltiles 2wid, 2wid+1)

  // ---- A fragments for the 4 base aggregates (held in registers) ----
  half8v base[4][4];  // [array][ks]
  {
    const _Float16* arrs[4] = {xh, a1, a2, a4};
#pragma unroll
    for (int t = 0; t < 4; ++t) {
      const _Float16* p = arrs[t] + (size_t)(node0 + mrow) * 128;
#pragma unroll
      for (int ks = 0; ks < 4; ++ks) {
        half4v lo = *(const half4v*)&p[ks * 32 + 4 * kg];
        half4v hi = *(const half4v*)&p[ks * 32 + 4 * kg + 16];
        base[t][ks] = __builtin_shufflevector(lo, hi, 0, 1, 2, 3, 4, 5, 6, 7);
      }
    }
  }

  // ---- 7 channel GEMMs, B frags coalesced from global (L2-hot) ----
#pragma unroll
  for (int c = 0; c < 7; ++c) {
    const int ia = (c < 4) ? c : (c - 4);
    const int ib = (c < 4) ? -1 : (c - 3);
    const _Float16* wc = WTs + (size_t)c * 16384;
    f32x4 acc0 = {0.f, 0.f, 0.f, 0.f}, acc1 = {0.f, 0.f, 0.f, 0.f};
#pragma unroll
    for (int ks = 0; ks < 4; ++ks) {
      half8v af = (ib < 0) ? base[ia][ks] : (base[ia][ks] - base[ib][ks]);
      half8v bf0 = *(const half8v*)&wc[(size_t)(2 * wid) * 2048 + ks * 512 + lane * 8];
      half8v bf1 = *(const half8v*)&wc[(size_t)(2 * wid + 1) * 2048 + ks * 512 + lane * 8];
      acc0 = __builtin_amdgcn_mfma_f32_16x16x32_f16(af, bf0, acc0, 0, 0, 0);
      acc1 = __builtin_amdgcn_mfma_f32_16x16x32_f16(af, bf1, acc1, 0, 0, 0);
    }
    const float* bias = (c < 4) ? (b_low + c * 128) : (b_band + (c - 4) * 128);
    float bv0 = bias[colw + mrow];
    float bv1 = bias[colw + 16 + mrow];
#pragma unroll
    for (int r = 0; r < 4; ++r) {
      sH[c][4 * kg + r][colw + mrow] = (_Float16)(acc0[r] + bv0);
      sH[c][4 * kg + r][colw + 16 + mrow] = (_Float16)(acc1[r] + bv1);
    }
  }
  __syncthreads();

  // ---- attention: 16 threads/node, 8 cols each; sH read ONCE to registers ----
  {
    const int n = tid >> 4;
    const int cb = (tid & 15) * 8;
    half8v hv[7];
#pragma unroll
    for (int c = 0; c < 7; ++c) hv[c] = *(const half8v*)&sH[c][n][cb];
    float apl[8], acl[8], apb[8], acb[8];
#pragma unroll
    for (int j = 0; j < 8; ++j) {
      apl[j] = apre_l[cb + j]; acl[j] = ach_l[cb + j];
      apb[j] = apre_b[cb + j]; acb[j] = ach_b[cb + j];
    }
    float dpl = 0.f, dpb = 0.f;
    float sarr[7];
#pragma unroll
    for (int c = 0; c < 7; ++c) {
      float sp = 0.f, sc = 0.f;
#pragma unroll
      for (int j = 0; j < 8; ++j) {
        float r = relu((float)hv[c][j]);
        if (c < 4) { sp += r * apl[j]; sc += r * acl[j]; }
        else       { sp += r * apb[j]; sc += r * acb[j]; }
      }
      if (c < 4) dpl += sp; else dpb += sp;
      sarr[c] = sc;
    }
    dpl *= 0.25f;
    dpb *= (1.0f / 3.0f);
#pragma unroll
    for (int m = 1; m <= 8; m <<= 1) {
      dpl += __shfl_xor(dpl, m);
      dpb += __shfl_xor(dpb, m);
#pragma unroll
      for (int c = 0; c < 7; ++c) sarr[c] += __shfl_xor(sarr[c], m);
    }
    float lg[7];
#pragma unroll
    for (int c = 0; c < 7; ++c)
      lg[c] = relu((c < 4 ? dpl : dpb) + sarr[c]);
    float ml = fmaxf(fmaxf(lg[0], lg[1]), fmaxf(lg[2], lg[3]));
    float e0 = expf(lg[0] - ml), e1 = expf(lg[1] - ml);
    float e2 = expf(lg[2] - ml), e3 = expf(lg[3] - ml);
    float invl = 1.0f / (e0 + e1 + e2 + e3);
    float mb = fmaxf(fmaxf(lg[4], lg[5]), lg[6]);
    float f4 = expf(lg[4] - mb), f5 = expf(lg[5] - mb), f6 = expf(lg[6] - mb);
    float invb = 1.0f / (f4 + f5 + f6);
    float al[7];
    al[0] = e0 * invl; al[1] = e1 * invl; al[2] = e2 * invl; al[3] = e3 * invl;
    al[4] = f4 * invb; al[5] = f5 * invb; al[6] = f6 * invb;
    half8v vl8, vb8;
#pragma unroll
    for (int j = 0; j < 8; ++j) {
      float vl = 0.f, vb = 0.f;
#pragma unroll
      for (int c = 0; c < 4; ++c) vl += al[c] * (float)hv[c][j];
#pragma unroll
      for (int c = 4; c < 7; ++c) vb += al[c] * (float)hv[c][j];
      vl8[j] = (_Float16)vl;
      vb8[j] = (_Float16)vb;
    }
    *(half8v*)&sV[n][cb] = vl8;
    *(half8v*)&sV[n][128 + cb] = vb8;
  }
  __syncthreads();

  // ---- MLP: [TM,256] @ [256,128], coalesced B frags ----
  f32x4 m0 = {0.f, 0.f, 0.f, 0.f}, m1 = {0.f, 0.f, 0.f, 0.f};
#pragma unroll
  for (int hh = 0; hh < 2; ++hh) {
    const _Float16* wm = WTs + (size_t)(7 + hh) * 16384;
#pragma unroll
    for (int ks = 0; ks < 4; ++ks) {
      int ka = hh * 128 + ks * 32 + 4 * kg;
      half4v aa = *(const half4v*)&sV[mrow][ka];
      half4v ab = *(const half4v*)&sV[mrow][ka + 16];
      half8v af = __builtin_shufflevector(aa, ab, 0, 1, 2, 3, 4, 5, 6, 7);
      half8v bf0 = *(const half8v*)&wm[(size_t)(2 * wid) * 2048 + ks * 512 + lane * 8];
      half8v bf1 = *(const half8v*)&wm[(size_t)(2 * wid + 1) * 2048 + ks * 512 + lane * 8];
      m0 = __builtin_amdgcn_mfma_f32_16x16x32_f16(af, bf0, m0, 0, 0, 0);
      m1 = __builtin_amdgcn_mfma_f32_16x16x32_f16(af, bf1, m1, 0, 0, 0);
    }
  }
  float bm0 = b_mlp[colw + mrow];
  float bm1 = b_mlp[colw + 16 + mrow];
#pragma unroll
  for (int r = 0; r < 4; ++r) {
    out[(size_t)(node0 + 4 * kg + r) * 128 + colw + mrow] = m0[r] + bm0;
    out[(size_t)(node0 + 4 * kg + r) * 128 + colw + 16 + mrow] = m1[r] + bm1;
  }
}

extern "C" void kernel_launch(void* const* d_in, const int* in_sizes, int n_in,
                              void* d_out, int out_size, void* d_ws, size_t ws_size,
                              hipStream_t stream) {
  const float* x      = (const float*)d_in[0];
  const int* ei       = (const int*)d_in[1];
  const float* W_low  = (const float*)d_in[2];
  const float* b_low  = (const float*)d_in[3];
  const float* W_band = (const float*)d_in[4];
  const float* b_band = (const float*)d_in[5];
  const float* apre_l = (const float*)d_in[6];
  const float* ach_l  = (const float*)d_in[7];
  const float* apre_b = (const float*)d_in[8];
  const float* ach_b  = (const float*)d_in[9];
  const float* W_mlp  = (const float*)d_in[10];
  const float* b_mlp  = (const float*)d_in[11];
  float* out = (float*)d_out;

  char* ws = (char*)d_ws;
  size_t off = 0;
  auto take = [&](size_t bytes) -> void* {
    void* p = ws + off;
    off = (off + bytes + 255) & ~(size_t)255;
    return p;
  };
  int*   deg2   = (int*)take((size_t)NT * 4);
  int*   fill2  = (int*)take((size_t)NT * 4);
  size_t zero_bytes = off;  // deg2 + fill2 region
  float* dinv   = (float*)take((size_t)NN * 4);
  int*   rowptr2 = (int*)take((size_t)(NT + 1) * 4);
  int*   bsum   = (int*)take((size_t)NSB * 4);
  int*   boff   = (int*)take((size_t)NSB * 4);
  int*   col    = (int*)take((size_t)NE * 4);
  float* wgt    = (float*)take((size_t)NE * 4);
  _Float16* xh  = (_Float16*)take((size_t)NN * 128 * 2);
  _Float16* a1h = (_Float16*)take((size_t)NN * 128 * 2);
  _Float16* a2h = (_Float16*)take((size_t)NN * 128 * 2);
  _Float16* a3h = (_Float16*)take((size_t)NN * 128 * 2);
  _Float16* a4h = (_Float16*)take((size_t)NN * 128 * 2);
  _Float16* WTs = (_Float16*)take((size_t)9 * 16384 * 2);
  (void)ws_size; (void)in_sizes; (void)n_in; (void)out_size;

  hipMemsetAsync(d_ws, 0, zero_bytes, stream);
  k_prep<<<9, 256, 0, stream>>>(W_low, W_band, W_mlp, WTs);
  k_x2h<<<(NN * 32 + 255) / 256, 256, 0, stream>>>(x, xh);
  k_deg2<<<(NE + 255) / 256, 256, 0, stream>>>(ei, deg2);
  k_dinv<<<(NN + 255) / 256, 256, 0, stream>>>(deg2, dinv);
  k_scanA<<<NSB, 256, 0, stream>>>(deg2, bsum);
  k_scanB<<<1, 256, 0, stream>>>(bsum, boff, rowptr2);
  k_scanC<<<NSB, 256, 0, stream>>>(deg2, boff, rowptr2);
  k_fill<<<(NE + 255) / 256, 256, 0, stream>>>(ei, dinv, rowptr2, fill2, col, wgt);
  k_hop16<<<(NN * 16 + 255) / 256, 256, 0, stream>>>(xh,  a1h, rowptr2, col, wgt);
  k_hop16<<<(NN * 16 + 255) / 256, 256, 0, stream>>>(a1h, a2h, rowptr2, col, wgt);
  k_hop16<<<(NN * 16 + 255) / 256, 256, 0, stream>>>(a2h, a3h, rowptr2, col, wgt);
  k_hop16<<<(NN * 16 + 255) / 256, 256, 0, stream>>>(a3h, a4h, rowptr2, col, wgt);
  k_fused<<<NN / TM, 256, 0, stream>>>(xh, a1h, a2h, a4h, WTs, b_low, b_band,
                                       apre_l, ach_l, apre_b, ach_b, b_mlp, out);
}

// Round 15
// 300.177 us; speedup vs baseline: 1.0304x; 1.0304x over previous
//
#include <hip/hip_runtime.h>
#include <math.h>

#define NN 50000
#define NE 800000
#define TM 16
#define NPAN 4
#define PSZ 12500   // nodes per src panel (3.2 MB of f16 rows, fits 4MB L2)
#define NT (NN * NPAN)
#define SCH 1024
#define NSB ((NT + SCH - 1) / SCH)   // 196 scan blocks

typedef _Float16 half4v __attribute__((ext_vector_type(4)));
typedef _Float16 half8v __attribute__((ext_vector_type(8)));
typedef float f32x4 __attribute__((ext_vector_type(4)));

__device__ __forceinline__ float relu(float v) { return fmaxf(v, 0.0f); }

// ---- degree count per (dst, src-panel) ----
__global__ __launch_bounds__(256) void k_deg2(const int* __restrict__ ei,
                                              int* __restrict__ deg2) {
  int e = blockIdx.x * 256 + threadIdx.x;
  if (e < NE) {
    int s = ei[e];
    int d = ei[NE + e];
    atomicAdd(&deg2[d * NPAN + s / PSZ], 1);
  }
}

// ---- d^-1/2 from panel-bucket degrees ----
__global__ __launch_bounds__(256) void k_dinv(const int* __restrict__ deg2,
                                              float* __restrict__ dinv) {
  int i = blockIdx.x * 256 + threadIdx.x;
  if (i < NN) {
    int d = deg2[i * NPAN] + deg2[i * NPAN + 1] + deg2[i * NPAN + 2] +
            deg2[i * NPAN + 3];
    dinv[i] = d > 0 ? 1.0f / sqrtf((float)d) : 0.0f;
  }
}

// ---- hierarchical scan, phase A: per-block chunk sums ----
__global__ __launch_bounds__(256) void k_scanA(const int* __restrict__ deg2,
                                               int* __restrict__ bsum) {
  const int tid = threadIdx.x;
  const int lane = tid & 63;
  const int wid = tid >> 6;
  int base = blockIdx.x * SCH + tid * 4;
  int s = 0;
  if (base + 3 < NT) {
    int4 v = *(const int4*)&deg2[base];
    s = v.x + v.y + v.z + v.w;
  } else {
#pragma unroll
    for (int j = 0; j < 4; ++j)
      if (base + j < NT) s += deg2[base + j];
  }
#pragma unroll
  for (int off = 1; off < 64; off <<= 1) s += __shfl_xor(s, off);
  __shared__ int ws[4];
  if (lane == 0) ws[wid] = s;
  __syncthreads();
  if (tid == 0) bsum[blockIdx.x] = ws[0] + ws[1] + ws[2] + ws[3];
}

// ---- phase B: single block exclusive-scans the NSB block sums ----
__global__ __launch_bounds__(256) void k_scanB(const int* __restrict__ bsum,
                                               int* __restrict__ boff,
                                               int* __restrict__ rowptr2) {
  const int tid = threadIdx.x;
  const int lane = tid & 63;
  const int wid = tid >> 6;
  int v = (tid < NSB) ? bsum[tid] : 0;
  int sum = v;
#pragma unroll
  for (int off = 1; off < 64; off <<= 1) {
    int t = __shfl_up(sum, off);
    if (lane >= off) sum += t;
  }
  __shared__ int ws[4];
  if (lane == 63) ws[wid] = sum;
  __syncthreads();
  int wbase = 0;
  for (int w = 0; w < wid; ++w) wbase += ws[w];
  int ex = wbase + sum - v;
  if (tid < NSB) boff[tid] = ex;
  if (tid == NSB - 1) rowptr2[NT] = ex + v;
}

// ---- phase C: per-block local exclusive scan + block offset ----
__global__ __launch_bounds__(256) void k_scanC(const int* __restrict__ deg2,
                                               const int* __restrict__ boff,
                                               int* __restrict__ rowptr2) {
  const int tid = threadIdx.x;
  const int lane = tid & 63;
  const int wid = tid >> 6;
  int base = blockIdx.x * SCH + tid * 4;
  int v0 = 0, v1 = 0, v2 = 0, v3 = 0;
  if (base + 3 < NT) {
    int4 v = *(const int4*)&deg2[base];
    v0 = v.x; v1 = v.y; v2 = v.z; v3 = v.w;
  } else {
    if (base + 0 < NT) v0 = deg2[base + 0];
    if (base + 1 < NT) v1 = deg2[base + 1];
    if (base + 2 < NT) v2 = deg2[base + 2];
    if (base + 3 < NT) v3 = deg2[base + 3];
  }
  int tsum = v0 + v1 + v2 + v3;
  int sum = tsum;
#pragma unroll
  for (int off = 1; off < 64; off <<= 1) {
    int t = __shfl_up(sum, off);
    if (lane >= off) sum += t;
  }
  __shared__ int ws[4];
  if (lane == 63) ws[wid] = sum;
  __syncthreads();
  int wbase = 0;
  for (int w = 0; w < wid; ++w) wbase += ws[w];
  int ex = boff[blockIdx.x] + wbase + sum - tsum;
  if (base + 0 < NT) rowptr2[base + 0] = ex;
  if (base + 1 < NT) rowptr2[base + 1] = ex + v0;
  if (base + 2 < NT) rowptr2[base + 2] = ex + v0 + v1;
  if (base + 3 < NT) rowptr2[base + 3] = ex + v0 + v1 + v2;
}

// ---- CSR fill into (dst, panel) buckets + edge weights ----
__global__ __launch_bounds__(256) void k_fill(const int* __restrict__ ei,
                                              const float* __restrict__ dinv,
                                              const int* __restrict__ rowptr2,
                                              int* __restrict__ fill2,
                                              int* __restrict__ col,
                                              float* __restrict__ wgt) {
  int e = blockIdx.x * 256 + threadIdx.x;
  if (e < NE) {
    int s = ei[e];
    int d = ei[NE + e];
    float w = dinv[s] * dinv[d] * 0.5f;
    int b = d * NPAN + s / PSZ;
    int pos = rowptr2[b] + atomicAdd(&fill2[b], 1);
    col[pos] = s;
    wgt[pos] = w;
  }
}

// ---- x (f32) -> xh (f16 [N][128]) ----
__global__ __launch_bounds__(256) void k_x2h(const float* __restrict__ x,
                                             _Float16* __restrict__ xh) {
  int i = blockIdx.x * 256 + threadIdx.x;
  if (i < NN * 32) {
    float4 v = ((const float4*)x)[i];
    half4v h;
    h[0] = (_Float16)v.x; h[1] = (_Float16)v.y;
    h[2] = (_Float16)v.z; h[3] = (_Float16)v.w;
    ((half4v*)xh)[i] = h;
  }
}

// ---- one hop (R13 best): 16 lanes/node; shfl-broadcast edges, 4-deep ----
__global__ __launch_bounds__(256) void k_hop16(const _Float16* __restrict__ in,
                                               _Float16* __restrict__ out,
                                               const int* __restrict__ rowptr2,
                                               const int* __restrict__ col,
                                               const float* __restrict__ wgt) {
  int g = (blockIdx.x * 256 + threadIdx.x) >> 4;  // node, 16 threads/node
  int lane = threadIdx.x & 15;
  if (g >= NN) return;
  const half8v* in8 = (const half8v*)in;  // 16B per lane, 256B per row
  half8v a = in8[(size_t)g * 16 + lane];
  float acc[8];
#pragma unroll
  for (int j = 0; j < 8; ++j) acc[j] = 0.5f * (float)a[j];
  int e0 = rowptr2[g * NPAN];
  int e1 = rowptr2[g * NPAN + NPAN];
  for (int base = e0; base < e1; base += 16) {
    int idx = base + lane;
    int idxc = idx < e1 ? idx : e1 - 1;   // clamp (value unused when masked)
    int cv = col[idxc];
    float wv = wgt[idxc];
    int cnt = e1 - base;
    if (cnt > 16) cnt = 16;
    int j = 0;
    for (; j + 4 <= cnt; j += 4) {
      int c0 = __shfl(cv, j, 16), c1 = __shfl(cv, j + 1, 16);
      int c2 = __shfl(cv, j + 2, 16), c3 = __shfl(cv, j + 3, 16);
      float w0 = __shfl(wv, j, 16), w1 = __shfl(wv, j + 1, 16);
      float w2 = __shfl(wv, j + 2, 16), w3 = __shfl(wv, j + 3, 16);
      half8v v0 = in8[(size_t)c0 * 16 + lane];
      half8v v1 = in8[(size_t)c1 * 16 + lane];
      half8v v2 = in8[(size_t)c2 * 16 + lane];
      half8v v3 = in8[(size_t)c3 * 16 + lane];
#pragma unroll
      for (int k = 0; k < 8; ++k)
        acc[k] += w0 * (float)v0[k] + w1 * (float)v1[k] +
                  w2 * (float)v2[k] + w3 * (float)v3[k];
    }
    for (; j < cnt; ++j) {
      int c = __shfl(cv, j, 16);
      float w = __shfl(wv, j, 16);
      half8v v = in8[(size_t)c * 16 + lane];
#pragma unroll
      for (int k = 0; k < 8; ++k) acc[k] += w * (float)v[k];
    }
  }
  half8v r;
#pragma unroll
  for (int j = 0; j < 8; ++j) r[j] = (_Float16)acc[j];
  ((half8v*)out)[(size_t)g * 16 + lane] = r;
}

// ---- prep: weights -> f16 fragment-order [m][ct(8)][ks(4)][lane(64)][8] ----
__global__ __launch_bounds__(256) void k_prep(const float* __restrict__ W_low,
                                              const float* __restrict__ W_band,
                                              const float* __restrict__ W_mlp,
                                              _Float16* __restrict__ WTs) {
  int m = blockIdx.x;  // 0..6 channels, 7..8 mlp chunks
  const float* src;
  if (m < 4)      src = W_low + m * 16384;
  else if (m < 7) src = W_band + (m - 4) * 16384;
  else            src = W_mlp + (m - 7) * 16384;
  _Float16* dst = WTs + (size_t)m * 16384;
  for (int s = threadIdx.x; s < 2048; s += 256) {
    int ct = s >> 8;          // col tile 0..7
    int ks = (s >> 6) & 3;    // k step 0..3
    int lane = s & 63;
    int mcol = lane & 15, kg = lane >> 4;
    int colc = ct * 16 + mcol;
    int k0 = ks * 32 + 4 * kg;
    _Float16* d = dst + (size_t)s * 8;
#pragma unroll
    for (int j = 0; j < 4; ++j) d[j] = (_Float16)src[(k0 + j) * 128 + colc];
#pragma unroll
    for (int j = 0; j < 4; ++j) d[4 + j] = (_Float16)src[(k0 + 16 + j) * 128 + colc];
  }
}

// ---- fused MFMA: channel-pipelined GEMMs + register attention + MLP ----
__global__ __launch_bounds__(256, 3) void k_fused(
    const _Float16* __restrict__ xh, const _Float16* __restrict__ a1,
    const _Float16* __restrict__ a2, const _Float16* __restrict__ a4,
    const _Float16* __restrict__ WTs,
    const float* __restrict__ b_low, const float* __restrict__ b_band,
    const float* __restrict__ apre_l, const float* __restrict__ ach_l,
    const float* __restrict__ apre_b, const float* __restrict__ ach_b,
    const float* __restrict__ b_mlp, float* __restrict__ out) {
  __shared__ _Float16 sH[7][TM][136]; // channel outputs  30464 B
  __shared__ _Float16 sV[TM][264];    // MLP input         8448 B

  const int tid = threadIdx.x;
  const int wid = tid >> 6;
  const int lane = tid & 63;
  const int mrow = lane & 15;   // node row in tile / out col in 16-tile
  const int kg = lane >> 4;     // k-group 0..3
  const int node0 = blockIdx.x * TM;
  const int colw = wid * 32;    // wave's 32-col slice (coltiles 2wid, 2wid+1)

  // ---- A fragments for the 4 base aggregates (held in registers) ----
  half8v base[4][4];  // [array][ks]
  {
    const _Float16* arrs[4] = {xh, a1, a2, a4};
#pragma unroll
    for (int t = 0; t < 4; ++t) {
      const _Float16* p = arrs[t] + (size_t)(node0 + mrow) * 128;
#pragma unroll
      for (int ks = 0; ks < 4; ++ks) {
        half4v lo = *(const half4v*)&p[ks * 32 + 4 * kg];
        half4v hi = *(const half4v*)&p[ks * 32 + 4 * kg + 16];
        base[t][ks] = __builtin_shufflevector(lo, hi, 0, 1, 2, 3, 4, 5, 6, 7);
      }
    }
  }

  // ---- 7 channel GEMMs with explicit next-channel B-frag prefetch ----
  half8v bfc[8];  // current channel B frags
  {
    const _Float16* wc = WTs;
#pragma unroll
    for (int ks = 0; ks < 4; ++ks) {
      bfc[ks] = *(const half8v*)&wc[(size_t)(2 * wid) * 2048 + ks * 512 + lane * 8];
      bfc[4 + ks] = *(const half8v*)&wc[(size_t)(2 * wid + 1) * 2048 + ks * 512 + lane * 8];
    }
  }
#pragma unroll
  for (int c = 0; c < 7; ++c) {
    half8v bfn[8];
    if (c < 6) {
      const _Float16* wn = WTs + (size_t)(c + 1) * 16384;
#pragma unroll
      for (int ks = 0; ks < 4; ++ks) {
        bfn[ks] = *(const half8v*)&wn[(size_t)(2 * wid) * 2048 + ks * 512 + lane * 8];
        bfn[4 + ks] = *(const half8v*)&wn[(size_t)(2 * wid + 1) * 2048 + ks * 512 + lane * 8];
      }
    }
    const int ia = (c < 4) ? c : (c - 4);
    const int ib = (c < 4) ? -1 : (c - 3);
    f32x4 acc0 = {0.f, 0.f, 0.f, 0.f}, acc1 = {0.f, 0.f, 0.f, 0.f};
#pragma unroll
    for (int ks = 0; ks < 4; ++ks) {
      half8v af = (ib < 0) ? base[ia][ks] : (base[ia][ks] - base[ib][ks]);
      acc0 = __builtin_amdgcn_mfma_f32_16x16x32_f16(af, bfc[ks], acc0, 0, 0, 0);
      acc1 = __builtin_amdgcn_mfma_f32_16x16x32_f16(af, bfc[4 + ks], acc1, 0, 0, 0);
    }
    const float* bias = (c < 4) ? (b_low + c * 128) : (b_band + (c - 4) * 128);
    float bv0 = bias[colw + mrow];
    float bv1 = bias[colw + 16 + mrow];
#pragma unroll
    for (int r = 0; r < 4; ++r) {
      sH[c][4 * kg + r][colw + mrow] = (_Float16)(acc0[r] + bv0);
      sH[c][4 * kg + r][colw + 16 + mrow] = (_Float16)(acc1[r] + bv1);
    }
    if (c < 6) {
#pragma unroll
      for (int q = 0; q < 8; ++q) bfc[q] = bfn[q];
    }
  }
  __syncthreads();

  // ---- attention: 16 threads/node, 8 cols each; sH read ONCE to registers ----
  {
    const int n = tid >> 4;
    const int cb = (tid & 15) * 8;
    half8v hv[7];
#pragma unroll
    for (int c = 0; c < 7; ++c) hv[c] = *(const half8v*)&sH[c][n][cb];
    float apl[8], acl[8], apb[8], acb[8];
#pragma unroll
    for (int j = 0; j < 8; ++j) {
      apl[j] = apre_l[cb + j]; acl[j] = ach_l[cb + j];
      apb[j] = apre_b[cb + j]; acb[j] = ach_b[cb + j];
    }
    float dpl = 0.f, dpb = 0.f;
    float sarr[7];
#pragma unroll
    for (int c = 0; c < 7; ++c) {
      float sp = 0.f, sc = 0.f;
#pragma unroll
      for (int j = 0; j < 8; ++j) {
        float r = relu((float)hv[c][j]);
        if (c < 4) { sp += r * apl[j]; sc += r * acl[j]; }
        else       { sp += r * apb[j]; sc += r * acb[j]; }
      }
      if (c < 4) dpl += sp; else dpb += sp;
      sarr[c] = sc;
    }
    dpl *= 0.25f;
    dpb *= (1.0f / 3.0f);
#pragma unroll
    for (int m = 1; m <= 8; m <<= 1) {
      dpl += __shfl_xor(dpl, m);
      dpb += __shfl_xor(dpb, m);
#pragma unroll
      for (int c = 0; c < 7; ++c) sarr[c] += __shfl_xor(sarr[c], m);
    }
    float lg[7];
#pragma unroll
    for (int c = 0; c < 7; ++c)
      lg[c] = relu((c < 4 ? dpl : dpb) + sarr[c]);
    float ml = fmaxf(fmaxf(lg[0], lg[1]), fmaxf(lg[2], lg[3]));
    float e0 = expf(lg[0] - ml), e1 = expf(lg[1] - ml);
    float e2 = expf(lg[2] - ml), e3 = expf(lg[3] - ml);
    float invl = 1.0f / (e0 + e1 + e2 + e3);
    float mb = fmaxf(fmaxf(lg[4], lg[5]), lg[6]);
    float f4 = expf(lg[4] - mb), f5 = expf(lg[5] - mb), f6 = expf(lg[6] - mb);
    float invb = 1.0f / (f4 + f5 + f6);
    float al[7];
    al[0] = e0 * invl; al[1] = e1 * invl; al[2] = e2 * invl; al[3] = e3 * invl;
    al[4] = f4 * invb; al[5] = f5 * invb; al[6] = f6 * invb;
    half8v vl8, vb8;
#pragma unroll
    for (int j = 0; j < 8; ++j) {
      float vl = 0.f, vb = 0.f;
#pragma unroll
      for (int c = 0; c < 4; ++c) vl += al[c] * (float)hv[c][j];
#pragma unroll
      for (int c = 4; c < 7; ++c) vb += al[c] * (float)hv[c][j];
      vl8[j] = (_Float16)vl;
      vb8[j] = (_Float16)vb;
    }
    *(half8v*)&sV[n][cb] = vl8;
    *(half8v*)&sV[n][128 + cb] = vb8;
  }
  __syncthreads();

  // ---- MLP: [TM,256] @ [256,128], coalesced B frags ----
  f32x4 m0 = {0.f, 0.f, 0.f, 0.f}, m1 = {0.f, 0.f, 0.f, 0.f};
#pragma unroll
  for (int hh = 0; hh < 2; ++hh) {
    const _Float16* wm = WTs + (size_t)(7 + hh) * 16384;
#pragma unroll
    for (int ks = 0; ks < 4; ++ks) {
      int ka = hh * 128 + ks * 32 + 4 * kg;
      half4v aa = *(const half4v*)&sV[mrow][ka];
      half4v ab = *(const half4v*)&sV[mrow][ka + 16];
      half8v af = __builtin_shufflevector(aa, ab, 0, 1, 2, 3, 4, 5, 6, 7);
      half8v bf0 = *(const half8v*)&wm[(size_t)(2 * wid) * 2048 + ks * 512 + lane * 8];
      half8v bf1 = *(const half8v*)&wm[(size_t)(2 * wid + 1) * 2048 + ks * 512 + lane * 8];
      m0 = __builtin_amdgcn_mfma_f32_16x16x32_f16(af, bf0, m0, 0, 0, 0);
      m1 = __builtin_amdgcn_mfma_f32_16x16x32_f16(af, bf1, m1, 0, 0, 0);
    }
  }
  float bm0 = b_mlp[colw + mrow];
  float bm1 = b_mlp[colw + 16 + mrow];
#pragma unroll
  for (int r = 0; r < 4; ++r) {
    out[(size_t)(node0 + 4 * kg + r) * 128 + colw + mrow] = m0[r] + bm0;
    out[(size_t)(node0 + 4 * kg + r) * 128 + colw + 16 + mrow] = m1[r] + bm1;
  }
}

extern "C" void kernel_launch(void* const* d_in, const int* in_sizes, int n_in,
                              void* d_out, int out_size, void* d_ws, size_t ws_size,
                              hipStream_t stream) {
  const float* x      = (const float*)d_in[0];
  const int* ei       = (const int*)d_in[1];
  const float* W_low  = (const float*)d_in[2];
  const float* b_low  = (const float*)d_in[3];
  const float* W_band = (const float*)d_in[4];
  const float* b_band = (const float*)d_in[5];
  const float* apre_l = (const float*)d_in[6];
  const float* ach_l  = (const float*)d_in[7];
  const float* apre_b = (const float*)d_in[8];
  const float* ach_b  = (const float*)d_in[9];
  const float* W_mlp  = (const float*)d_in[10];
  const float* b_mlp  = (const float*)d_in[11];
  float* out = (float*)d_out;

  char* ws = (char*)d_ws;
  size_t off = 0;
  auto take = [&](size_t bytes) -> void* {
    void* p = ws + off;
    off = (off + bytes + 255) & ~(size_t)255;
    return p;
  };
  int*   deg2   = (int*)take((size_t)NT * 4);
  int*   fill2  = (int*)take((size_t)NT * 4);
  size_t zero_bytes = off;  // deg2 + fill2 region
  float* dinv   = (float*)take((size_t)NN * 4);
  int*   rowptr2 = (int*)take((size_t)(NT + 1) * 4);
  int*   bsum   = (int*)take((size_t)NSB * 4);
  int*   boff   = (int*)take((size_t)NSB * 4);
  int*   col    = (int*)take((size_t)NE * 4);
  float* wgt    = (float*)take((size_t)NE * 4);
  _Float16* xh  = (_Float16*)take((size_t)NN * 128 * 2);
  _Float16* a1h = (_Float16*)take((size_t)NN * 128 * 2);
  _Float16* a2h = (_Float16*)take((size_t)NN * 128 * 2);
  _Float16* a3h = (_Float16*)take((size_t)NN * 128 * 2);
  _Float16* a4h = (_Float16*)take((size_t)NN * 128 * 2);
  _Float16* WTs = (_Float16*)take((size_t)9 * 16384 * 2);
  (void)ws_size; (void)in_sizes; (void)n_in; (void)out_size;

  hipMemsetAsync(d_ws, 0, zero_bytes, stream);
  k_prep<<<9, 256, 0, stream>>>(W_low, W_band, W_mlp, WTs);
  k_x2h<<<(NN * 32 + 255) / 256, 256, 0, stream>>>(x, xh);
  k_deg2<<<(NE + 255) / 256, 256, 0, stream>>>(ei, deg2);
  k_dinv<<<(NN + 255) / 256, 256, 0, stream>>>(deg2, dinv);
  k_scanA<<<NSB, 256, 0, stream>>>(deg2, bsum);
  k_scanB<<<1, 256, 0, stream>>>(bsum, boff, rowptr2);
  k_scanC<<<NSB, 256, 0, stream>>>(deg2, boff, rowptr2);
  k_fill<<<(NE + 255) / 256, 256, 0, stream>>>(ei, dinv, rowptr2, fill2, col, wgt);
  k_hop16<<<(NN * 16 + 255) / 256, 256, 0, stream>>>(xh,  a1h, rowptr2, col, wgt);
  k_hop16<<<(NN * 16 + 255) / 256, 256, 0, stream>>>(a1h, a2h, rowptr2, col, wgt);
  k_hop16<<<(NN * 16 + 255) / 256, 256, 0, stream>>>(a2h, a3h, rowptr2, col, wgt);
  k_hop16<<<(NN * 16 + 255) / 256, 256, 0, stream>>>(a3h, a4h, rowptr2, col, wgt);
  k_fused<<<NN / TM, 256, 0, stream>>>(xh, a1h, a2h, a4h, WTs, b_low, b_band,
                                       apre_l, ach_l, apre_b, ach_b, b_mlp, out);
}